// Round 5
// baseline (101.267 us; speedup 1.0000x reference)
//
#include <hip/hip_runtime.h>
#include <hip/hip_bf16.h>
#include <stdint.h>

#define NB    32
#define CIN   128
#define HIN   56
#define HW    (HIN*HIN)     // 3136
#define OCH   256
#define OHW   54
#define SPB   (OHW*OHW)     // 2916
#define KSZ   (CIN*9)       // 1152 = GEMM K
#define BM    256           // oc rows per block (= OCH)
#define BN    256           // flattened (n,sp) cols per block
#define BK    64
#define NKS   (KSZ/BK)      // 18 K-tiles
#define TOTC  (NB*SPB)      // 93312
#define NT    365           // ceil(93312/256)

typedef __attribute__((ext_vector_type(8))) short bf16x8;
typedef __attribute__((ext_vector_type(4))) float f32x4;

typedef __attribute__((address_space(1))) const uint32_t g_u32;
typedef __attribute__((address_space(3))) uint32_t l_u32;
static __device__ __forceinline__ void gl_lds16(const void* g, void* l) {
    __builtin_amdgcn_global_load_lds((g_u32*)g, (l_u32*)l, 16, 0, 0);
}

// ---- pre-pass 1: x NCHW f32 -> NHWC bf16 ----
__global__ void xpose_cast(const float* __restrict__ x, __hip_bfloat16* __restrict__ xt) {
    __shared__ float tile[32][33];
    const int hw0 = blockIdx.x * 32;
    const int c0  = blockIdx.y * 32;
    const int n   = blockIdx.z;
    const int tx = threadIdx.x, ty = threadIdx.y;
    const float* xp = x + ((size_t)n*CIN + c0)*HW + hw0;
    #pragma unroll
    for (int i = ty; i < 32; i += 8)
        tile[i][tx] = xp[(size_t)i*HW + tx];
    __syncthreads();
    const int t = ty*32 + tx;
    const int hwl = t >> 3, q = t & 7;
    ushort4 v;
    v.x = __bfloat16_as_ushort(__float2bfloat16(tile[q*4+0][hwl]));
    v.y = __bfloat16_as_ushort(__float2bfloat16(tile[q*4+1][hwl]));
    v.z = __bfloat16_as_ushort(__float2bfloat16(tile[q*4+2][hwl]));
    v.w = __bfloat16_as_ushort(__float2bfloat16(tile[q*4+3][hwl]));
    __hip_bfloat16* op = xt + ((size_t)n*HW + hw0 + hwl)*CIN + c0 + q*4;
    *(ushort4*)op = v;
}

// ---- pre-pass 2: weight OIHW f32 -> [oc][(kh*3+kw)*128+ic] bf16 ----
__global__ void wcast(const float* __restrict__ w, __hip_bfloat16* __restrict__ wt) {
    int tid = blockIdx.x*256 + threadIdx.x;
    if (tid >= OCH*KSZ) return;
    int oc = tid / KSZ, r = tid % KSZ;
    int pos = r >> 7, ic = r & 127;
    wt[tid] = __float2bfloat16(w[((size_t)(oc*CIN + ic))*9 + pos]);
}

// ---- main: implicit-GEMM bf16 MFMA conv, m201-geometry 4-phase/K-tile ----
// grid (365), block 512 = 8 waves (2M x 4N), per-wave 128x64 output
__global__ __launch_bounds__(512, 2)
void conv_mfma(const __hip_bfloat16* __restrict__ xt,
               const __hip_bfloat16* __restrict__ wt,
               const float* __restrict__ bias,
               float* __restrict__ out) {
    // double buffer: (A 256x64 + B 256x64) bf16 = 64KB x 2 = 128KB
    // granule-XOR swizzle: linear gl_lds dest + inverse-swizzled SOURCE + swizzled read
    __shared__ uint4 smem[8192];

    const int t = threadIdx.x;
    const int tile = blockIdx.x;
    const int lane = t & 63, wid = t >> 6;
    const int wm = wid >> 2, wn = wid & 3;     // wm: 128-row half, wn: 64-col quarter
    const int lr = lane & 15, lq = lane >> 4;

    // staging sources: 4 A-granule-sets + 4 B-granule-sets (p = i*512+t over 2048 granules)
    const __hip_bfloat16* asrc[4];
    const __hip_bfloat16* bsrc[4];
    #pragma unroll
    for (int i = 0; i < 4; ++i) {
        int p = i*512 + t;
        int row = p >> 3, g = (p & 7) ^ (row & 7);
        asrc[i] = wt + (size_t)row*KSZ + g*8;
        int colg = tile*BN + row; if (colg >= TOTC) colg = TOTC - 1;   // clamp pad cols
        int n = colg / SPB, rem = colg - n*SPB;
        int oh = rem / OHW, ow = rem - oh*OHW;
        bsrc[i] = xt + ((size_t)(n*HIN + oh)*HIN + ow)*CIN + g*8;
    }

    auto issueTile = [&](int ks) {   // all 8 loads for tile ks -> buf[ks&1]
        uint4* Ab = smem + (ks & 1)*4096;
        uint4* Bb = Ab + 2048;
        const int pos = ks >> 1;
        const int kh = pos / 3, kw = pos - kh*3;
        const int aoff = ks*BK;
        const int boff = (kh*HIN + kw)*CIN + (ks & 1)*64;
        #pragma unroll
        for (int i = 0; i < 4; ++i) gl_lds16(asrc[i] + aoff, Ab + i*512 + t);
        #pragma unroll
        for (int i = 0; i < 4; ++i) gl_lds16(bsrc[i] + boff, Bb + i*512 + t);
    };

    f32x4 acc[8][4];
    #pragma unroll
    for (int i = 0; i < 8; ++i)
        #pragma unroll
        for (int j = 0; j < 4; ++j)
            acc[i][j] = (f32x4){0.f, 0.f, 0.f, 0.f};

    issueTile(0);
    asm volatile("s_waitcnt vmcnt(0)" ::: "memory");
    __builtin_amdgcn_s_barrier();

    #define MFMA_BF16 __builtin_amdgcn_mfma_f32_16x16x32_bf16
    #define RD_A(dst, MIB, KK) \
        { int ra = wm*128 + (MIB)*16 + lr; \
          dst = *(bf16x8*)&Ab[ra*8 + (((KK)*4 + lq) ^ (ra & 7))]; }
    #define RD_B(dst, NI, KK) \
        { int rb = wn*64 + (NI)*16 + lr; \
          dst = *(bf16x8*)&Bb[rb*8 + (((KK)*4 + lq) ^ (rb & 7))]; }
    #define PH_SYNC() \
        __builtin_amdgcn_s_barrier(); \
        asm volatile("s_waitcnt lgkmcnt(0)"); \
        __builtin_amdgcn_sched_barrier(0);
    #define MFMA16(AARR, MIB, BARR) \
        __builtin_amdgcn_s_setprio(1); \
        _Pragma("unroll") \
        for (int ii = 0; ii < 4; ++ii) \
            _Pragma("unroll") \
            for (int ni = 0; ni < 4; ++ni) \
                acc[(MIB)+ii][ni] = MFMA_BF16(AARR[ii], BARR[ni], acc[(MIB)+ii][ni], 0, 0, 0); \
        __builtin_amdgcn_s_setprio(0); \
        __builtin_amdgcn_s_barrier();

    for (int ks = 0; ks < NKS; ++ks) {
        const uint4* Ab = smem + (ks & 1)*4096;
        const uint4* Bb = Ab + 2048;
        bf16x8 a[4], b[4];

        // phase 0: kk=0, mi 0-3 (8 ds_read) + front-load next tile's 8 gl_lds
        RD_A(a[0], 0, 0) RD_A(a[1], 1, 0) RD_A(a[2], 2, 0) RD_A(a[3], 3, 0)
        RD_B(b[0], 0, 0) RD_B(b[1], 1, 0) RD_B(b[2], 2, 0) RD_B(b[3], 3, 0)
        if (ks + 1 < NKS) issueTile(ks + 1);
        PH_SYNC()
        MFMA16(a, 0, b)

        // phase 1: kk=0, mi 4-7 (4 ds_read; b reused)
        RD_A(a[0], 4, 0) RD_A(a[1], 5, 0) RD_A(a[2], 6, 0) RD_A(a[3], 7, 0)
        PH_SYNC()
        MFMA16(a, 4, b)

        // phase 2: kk=1, mi 0-3 (8 ds_read)
        RD_A(a[0], 0, 1) RD_A(a[1], 1, 1) RD_A(a[2], 2, 1) RD_A(a[3], 3, 1)
        RD_B(b[0], 0, 1) RD_B(b[1], 1, 1) RD_B(b[2], 2, 1) RD_B(b[3], 3, 1)
        PH_SYNC()
        MFMA16(a, 0, b)

        // phase 3: kk=1, mi 4-7 (4 ds_read); certify next tile before its first read
        RD_A(a[0], 4, 1) RD_A(a[1], 5, 1) RD_A(a[2], 6, 1) RD_A(a[3], 7, 1)
        PH_SYNC()
        __builtin_amdgcn_s_setprio(1);
        #pragma unroll
        for (int ii = 0; ii < 4; ++ii)
            #pragma unroll
            for (int ni = 0; ni < 4; ++ni)
                acc[4+ii][ni] = MFMA_BF16(a[ii], b[ni], acc[4+ii][ni], 0, 0, 0);
        __builtin_amdgcn_s_setprio(0);
        if (ks + 1 < NKS)
            asm volatile("s_waitcnt vmcnt(0)" ::: "memory");  // issued 3.5 phases ago
        __builtin_amdgcn_s_barrier();
    }

    // --- epilogue: LDS restage [64][260] per oc-quarter, coalesced float4 stores ---
    float (*eps)[260] = (float (*)[260])smem;
    const int cl4 = (t & 63) * 4;
    const int rsub = t >> 6;
    const int colg = tile*BN + cl4;
    int nn = 0, sp = 0;
    if (colg < TOTC) { nn = colg / SPB; sp = colg - nn*SPB; }
    #pragma unroll
    for (int h = 0; h < 4; ++h) {
        if (wm == (h >> 1)) {
            const int mib = (h & 1) * 4;
            #pragma unroll
            for (int ii = 0; ii < 4; ++ii) {
                int rl = ii*16 + lq*4;
                #pragma unroll
                for (int ni = 0; ni < 4; ++ni) {
                    int cl = wn*64 + ni*16 + lr;
                    #pragma unroll
                    for (int r = 0; r < 4; ++r)
                        eps[rl + r][cl] = acc[mib + ii][ni][r];
                }
            }
        }
        __syncthreads();
        if (colg < TOTC) {
            #pragma unroll
            for (int pass = 0; pass < 8; ++pass) {
                int rl = pass*8 + rsub;
                int rg = h*64 + rl;
                f32x4 v = *(f32x4*)&eps[rl][cl4];
                v = v + bias[rg];
                *(f32x4*)&out[((size_t)nn*OCH + rg)*SPB + sp] = v;
            }
        }
        __syncthreads();
    }
}

// ---- fallback: direct fp32 conv ----
__global__ void conv_naive(const float* __restrict__ x, const float* __restrict__ w,
                           const float* __restrict__ bias, float* __restrict__ out) {
    size_t tid = (size_t)blockIdx.x*256 + threadIdx.x;
    const size_t total = (size_t)NB*OCH*SPB;
    if (tid >= total) return;
    int col = (int)(tid % SPB);
    int oc  = (int)((tid / SPB) % OCH);
    int n   = (int)(tid / ((size_t)SPB*OCH));
    int oh = col / OHW, ow = col % OHW;
    float s = bias[oc];
    for (int ic = 0; ic < CIN; ++ic)
        #pragma unroll
        for (int kh = 0; kh < 3; ++kh)
            #pragma unroll
            for (int kw = 0; kw < 3; ++kw)
                s += x[((size_t)(n*CIN+ic)*HIN + oh+kh)*HIN + ow+kw]
                   * w[((size_t)(oc*CIN+ic)*3 + kh)*3 + kw];
    out[tid] = s;
}

extern "C" void kernel_launch(void* const* d_in, const int* in_sizes, int n_in,
                              void* d_out, int out_size, void* d_ws, size_t ws_size,
                              hipStream_t stream) {
    const float* x    = (const float*)d_in[0];
    const float* w    = (const float*)d_in[1];
    const float* bias = (const float*)d_in[2];
    float* out = (float*)d_out;

    const size_t xt_bytes = (size_t)NB*HW*CIN*sizeof(__hip_bfloat16);
    const size_t wt_bytes = (size_t)OCH*KSZ*sizeof(__hip_bfloat16);

    if (ws_size >= xt_bytes + wt_bytes) {
        __hip_bfloat16* xt  = (__hip_bfloat16*)d_ws;
        __hip_bfloat16* wtp = (__hip_bfloat16*)((char*)d_ws + xt_bytes);
        hipLaunchKernelGGL(xpose_cast, dim3(HW/32, CIN/32, NB), dim3(32, 8), 0, stream, x, xt);
        hipLaunchKernelGGL(wcast, dim3((OCH*KSZ + 255)/256), dim3(256), 0, stream, w, wtp);
        hipLaunchKernelGGL(conv_mfma, dim3(NT), dim3(512), 0, stream, xt, wtp, bias, out);
    } else {
        size_t total = (size_t)NB*OCH*SPB;
        hipLaunchKernelGGL(conv_naive, dim3((unsigned)((total + 255)/256)), dim3(256), 0, stream,
                           x, w, bias, out);
    }
}

// Round 6
// 101.112 us; speedup vs baseline: 1.0015x; 1.0015x over previous
//
#include <hip/hip_runtime.h>
#include <hip/hip_bf16.h>
#include <stdint.h>

#define NB    32
#define CIN   128
#define HIN   56
#define HW    (HIN*HIN)     // 3136
#define OCH   256
#define OHW   54
#define SPB   (OHW*OHW)     // 2916
#define KSZ   (CIN*9)       // 1152 = GEMM K
#define BM    256           // oc rows per block (= OCH)
#define BN    256           // flattened (n,sp) cols per block
#define BK    64
#define NKS   (KSZ/BK)      // 18 K-tiles
#define TOTC  (NB*SPB)      // 93312
#define NT    365           // ceil(93312/256)

typedef __attribute__((ext_vector_type(8))) short bf16x8;
typedef __attribute__((ext_vector_type(4))) float f32x4;

typedef __attribute__((address_space(1))) const uint32_t g_u32;
typedef __attribute__((address_space(3))) uint32_t l_u32;
static __device__ __forceinline__ void gl_lds16(const void* g, void* l) {
    __builtin_amdgcn_global_load_lds((g_u32*)g, (l_u32*)l, 16, 0, 0);
}

// ---- pre-pass 1: x NCHW f32 -> NHWC bf16 ----
__global__ void xpose_cast(const float* __restrict__ x, __hip_bfloat16* __restrict__ xt) {
    __shared__ float tile[32][33];
    const int hw0 = blockIdx.x * 32;
    const int c0  = blockIdx.y * 32;
    const int n   = blockIdx.z;
    const int tx = threadIdx.x, ty = threadIdx.y;
    const float* xp = x + ((size_t)n*CIN + c0)*HW + hw0;
    #pragma unroll
    for (int i = ty; i < 32; i += 8)
        tile[i][tx] = xp[(size_t)i*HW + tx];
    __syncthreads();
    const int t = ty*32 + tx;
    const int hwl = t >> 3, q = t & 7;
    ushort4 v;
    v.x = __bfloat16_as_ushort(__float2bfloat16(tile[q*4+0][hwl]));
    v.y = __bfloat16_as_ushort(__float2bfloat16(tile[q*4+1][hwl]));
    v.z = __bfloat16_as_ushort(__float2bfloat16(tile[q*4+2][hwl]));
    v.w = __bfloat16_as_ushort(__float2bfloat16(tile[q*4+3][hwl]));
    __hip_bfloat16* op = xt + ((size_t)n*HW + hw0 + hwl)*CIN + c0 + q*4;
    *(ushort4*)op = v;
}

// ---- pre-pass 2: weight OIHW f32 -> [oc][(kh*3+kw)*128+ic] bf16 ----
__global__ void wcast(const float* __restrict__ w, __hip_bfloat16* __restrict__ wt) {
    int tid = blockIdx.x*256 + threadIdx.x;
    if (tid >= OCH*KSZ) return;
    int oc = tid / KSZ, r = tid % KSZ;
    int pos = r >> 7, ic = r & 127;
    wt[tid] = __float2bfloat16(w[((size_t)(oc*CIN + ic))*9 + pos]);
}

// ---- main: implicit-GEMM bf16 MFMA conv, 4-phase + TRUE counted vmcnt ----
// grid (365), block 512 = 8 waves (2M x 4N), per-wave 128x64 output
// LDS tile layout (per matrix, per buffer): [kk-half][row 0..255][granule 0..3]
//   granule g holds logical lq = g ^ (row&3)  (bank-uniform; gl_lds-compatible:
//   dest lane-linear, swizzle folded into per-lane SOURCE offset)
__global__ __launch_bounds__(512, 2)
void conv_mfma(const __hip_bfloat16* __restrict__ xt,
               const __hip_bfloat16* __restrict__ wt,
               const float* __restrict__ bias,
               float* __restrict__ out) {
    __shared__ uint4 smem[8192];   // 2 buf x (A 2048 + B 2048 granules) = 128KB

    const int t = threadIdx.x;
    const int tile = blockIdx.x;
    const int lane = t & 63, wid = t >> 6;
    const int wm = wid >> 2, wn = wid & 3;
    const int lr = lane & 15, lq = lane >> 4;

    // staging precompute: issue i covers granules q = i*512 + t of a 1024-granule unit
    const __hip_bfloat16* aptr[2];
    const __hip_bfloat16* bptr[2];
    #pragma unroll
    for (int i = 0; i < 2; ++i) {
        int q = i*512 + t;
        int row = q >> 2, j = q & 3;
        int ls = j ^ (row & 3);                  // logical granule staged at slot q
        aptr[i] = wt + (size_t)row*KSZ + ls*8;
        int colg = tile*BN + row; if (colg >= TOTC) colg = TOTC - 1;
        int n = colg / SPB, rem = colg - n*SPB;
        int oh = rem / OHW, ow = rem - oh*OHW;
        bptr[i] = xt + ((size_t)(n*HIN + oh)*HIN + ow)*CIN + ls*8;
    }

    // stage unit = (matrix, kk-half) of tile ks: 1024 contiguous dest granules
    auto issueU = [&](int ks, int mat, int X) {
        uint4* dst = smem + (ks & 1)*4096 + mat*2048 + X*1024 + t;
        if (mat == 0) {
            const int off = ks*BK + X*32;
            gl_lds16(aptr[0] + off, dst);
            gl_lds16(aptr[1] + off, dst + 512);
        } else {
            const int pos = ks >> 1;
            const int kh = pos / 3, kw = pos - kh*3;
            const int off = (kh*HIN + kw)*CIN + (ks & 1)*64 + X*32;
            gl_lds16(bptr[0] + off, dst);
            gl_lds16(bptr[1] + off, dst + 512);
        }
    };

    f32x4 acc[8][4];
    #pragma unroll
    for (int i = 0; i < 8; ++i)
        #pragma unroll
        for (int j = 0; j < 4; ++j)
            acc[i][j] = (f32x4){0.f, 0.f, 0.f, 0.f};

    #define MFMA_BF16 __builtin_amdgcn_mfma_f32_16x16x32_bf16
    #define RD_A4(arr, MIB, KK) \
        _Pragma("unroll") \
        for (int ii = 0; ii < 4; ++ii) { \
            int ra = wm*128 + ((MIB)+ii)*16 + lr; \
            arr[ii] = *(bf16x8*)&Ab[(KK)*1024 + ra*4 + (lq ^ (ra & 3))]; \
        }
    #define RD_B4(arr, KK) \
        _Pragma("unroll") \
        for (int ni = 0; ni < 4; ++ni) { \
            int rb = wn*64 + ni*16 + lr; \
            arr[ni] = *(bf16x8*)&Bb[(KK)*1024 + rb*4 + (lq ^ (rb & 3))]; \
        }
    #define PH_OPEN() \
        __builtin_amdgcn_s_barrier(); \
        asm volatile("s_waitcnt lgkmcnt(0)"); \
        __builtin_amdgcn_sched_barrier(0);
    #define MFMA_BLK(AARR, MIB, BARR) \
        __builtin_amdgcn_s_setprio(1); \
        _Pragma("unroll") \
        for (int ii = 0; ii < 4; ++ii) \
            _Pragma("unroll") \
            for (int ni = 0; ni < 4; ++ni) \
                acc[(MIB)+ii][ni] = MFMA_BF16(AARR[ii], BARR[ni], acc[(MIB)+ii][ni], 0, 0, 0); \
        __builtin_amdgcn_s_setprio(0);

    // prologue: all 4 units of tile 0; certify U0 pair, leave U1 pair in flight
    issueU(0, 0, 0); issueU(0, 1, 0); issueU(0, 0, 1); issueU(0, 1, 1);
    asm volatile("s_waitcnt vmcnt(4)" ::: "memory");
    __builtin_amdgcn_s_barrier();
    __builtin_amdgcn_sched_barrier(0);

    for (int ks = 0; ks < NKS; ++ks) {
        const uint4* Ab = smem + (ks & 1)*4096;
        const uint4* Bb = Ab + 2048;
        const bool pf = (ks + 1 < NKS);
        bf16x8 a[4], b[4];

        // ---- ph0: kk0, mi0-3 (8 ds_read) ; stage A-k0(ks+1)
        RD_A4(a, 0, 0) RD_B4(b, 0)
        if (pf) issueU(ks + 1, 0, 0);
        PH_OPEN()
        MFMA_BLK(a, 0, b)
        __builtin_amdgcn_s_barrier();

        // ---- ph1: kk0, mi4-7 (4 ds_read; b reused) ; stage B-k0(ks+1)
        // certify: current tile's kk1 (issued last tile ph2/ph3); leave U0(ks+1) in flight
        RD_A4(a, 4, 0)
        if (pf) issueU(ks + 1, 1, 0);
        PH_OPEN()
        MFMA_BLK(a, 4, b)
        if (pf) asm volatile("s_waitcnt vmcnt(4)" ::: "memory");
        else    asm volatile("s_waitcnt vmcnt(0)" ::: "memory");
        __builtin_amdgcn_s_barrier();
        __builtin_amdgcn_sched_barrier(0);   // pin ph2 ds_reads below this barrier

        // ---- ph2: kk1, mi0-3 (8 ds_read) ; stage A-k1(ks+1)
        RD_A4(a, 0, 1) RD_B4(b, 1)
        if (pf) issueU(ks + 1, 0, 1);
        PH_OPEN()
        MFMA_BLK(a, 0, b)
        __builtin_amdgcn_s_barrier();

        // ---- ph3: kk1, mi4-7 (4 ds_read) ; stage B-k1(ks+1)
        // certify: next tile's kk0 (issued ph0/ph1); leave U1(ks+1) in flight
        RD_A4(a, 4, 1)
        if (pf) issueU(ks + 1, 1, 1);
        PH_OPEN()
        MFMA_BLK(a, 4, b)
        if (pf) asm volatile("s_waitcnt vmcnt(4)" ::: "memory");
        __builtin_amdgcn_s_barrier();
        __builtin_amdgcn_sched_barrier(0);   // pin next ph0 ds_reads below
    }

    // --- epilogue: LDS restage [64][260] per oc-quarter, coalesced float4 stores ---
    float (*eps)[260] = (float (*)[260])smem;
    const int cl4 = (t & 63) * 4;
    const int rsub = t >> 6;
    const int colg = tile*BN + cl4;
    int nn = 0, sp = 0;
    if (colg < TOTC) { nn = colg / SPB; sp = colg - nn*SPB; }
    #pragma unroll
    for (int h = 0; h < 4; ++h) {
        if (wm == (h >> 1)) {
            const int mib = (h & 1) * 4;
            #pragma unroll
            for (int ii = 0; ii < 4; ++ii) {
                int rl = ii*16 + lq*4;
                #pragma unroll
                for (int ni = 0; ni < 4; ++ni) {
                    int cl = wn*64 + ni*16 + lr;
                    #pragma unroll
                    for (int r = 0; r < 4; ++r)
                        eps[rl + r][cl] = acc[mib + ii][ni][r];
                }
            }
        }
        __syncthreads();
        if (colg < TOTC) {
            #pragma unroll
            for (int pass = 0; pass < 8; ++pass) {
                int rl = pass*8 + rsub;
                int rg = h*64 + rl;
                f32x4 v = *(f32x4*)&eps[rl][cl4];
                v = v + bias[rg];
                *(f32x4*)&out[((size_t)nn*OCH + rg)*SPB + sp] = v;
            }
        }
        __syncthreads();
    }
}

// ---- fallback: direct fp32 conv ----
__global__ void conv_naive(const float* __restrict__ x, const float* __restrict__ w,
                           const float* __restrict__ bias, float* __restrict__ out) {
    size_t tid = (size_t)blockIdx.x*256 + threadIdx.x;
    const size_t total = (size_t)NB*OCH*SPB;
    if (tid >= total) return;
    int col = (int)(tid % SPB);
    int oc  = (int)((tid / SPB) % OCH);
    int n   = (int)(tid / ((size_t)SPB*OCH));
    int oh = col / OHW, ow = col % OHW;
    float s = bias[oc];
    for (int ic = 0; ic < CIN; ++ic)
        #pragma unroll
        for (int kh = 0; kh < 3; ++kh)
            #pragma unroll
            for (int kw = 0; kw < 3; ++kw)
                s += x[((size_t)(n*CIN+ic)*HIN + oh+kh)*HIN + ow+kw]
                   * w[((size_t)(oc*CIN+ic)*3 + kh)*3 + kw];
    out[tid] = s;
}

extern "C" void kernel_launch(void* const* d_in, const int* in_sizes, int n_in,
                              void* d_out, int out_size, void* d_ws, size_t ws_size,
                              hipStream_t stream) {
    const float* x    = (const float*)d_in[0];
    const float* w    = (const float*)d_in[1];
    const float* bias = (const float*)d_in[2];
    float* out = (float*)d_out;

    const size_t xt_bytes = (size_t)NB*HW*CIN*sizeof(__hip_bfloat16);
    const size_t wt_bytes = (size_t)OCH*KSZ*sizeof(__hip_bfloat16);

    if (ws_size >= xt_bytes + wt_bytes) {
        __hip_bfloat16* xt  = (__hip_bfloat16*)d_ws;
        __hip_bfloat16* wtp = (__hip_bfloat16*)((char*)d_ws + xt_bytes);
        hipLaunchKernelGGL(xpose_cast, dim3(HW/32, CIN/32, NB), dim3(32, 8), 0, stream, x, xt);
        hipLaunchKernelGGL(wcast, dim3((OCH*KSZ + 255)/256), dim3(256), 0, stream, w, wtp);
        hipLaunchKernelGGL(conv_mfma, dim3(NT), dim3(512), 0, stream, xt, wtp, bias, out);
    } else {
        size_t total = (size_t)NB*OCH*SPB;
        hipLaunchKernelGGL(conv_naive, dim3((unsigned)((total + 255)/256)), dim3(256), 0, stream,
                           x, w, bias, out);
    }
}

// Round 7
// 94.641 us; speedup vs baseline: 1.0700x; 1.0684x over previous
//
#include <hip/hip_runtime.h>
#include <hip/hip_bf16.h>
#include <stdint.h>

#define NB    32
#define CIN   128
#define HIN   56
#define HW    (HIN*HIN)     // 3136
#define OCH   256
#define OHW   54
#define SPB   (OHW*OHW)     // 2916
#define KSZ   (CIN*9)       // 1152 = GEMM K
#define BM    256           // oc rows per block (= OCH)
#define BN    256           // flattened (n,sp) cols per block
#define BK    32
#define NKS   (KSZ/BK)      // 36 K-tiles
#define TOTC  (NB*SPB)      // 93312
#define NT    365           // ceil(93312/256)

typedef __attribute__((ext_vector_type(8))) short bf16x8;
typedef __attribute__((ext_vector_type(4))) float f32x4;

typedef __attribute__((address_space(1))) const uint32_t g_u32;
typedef __attribute__((address_space(3))) uint32_t l_u32;
static __device__ __forceinline__ void gl_lds16(const void* g, void* l) {
    __builtin_amdgcn_global_load_lds((g_u32*)g, (l_u32*)l, 16, 0, 0);
}

// ---- pre-pass 1: x NCHW f32 -> NHWC bf16 ----
__global__ void xpose_cast(const float* __restrict__ x, __hip_bfloat16* __restrict__ xt) {
    __shared__ float tile[32][33];
    const int hw0 = blockIdx.x * 32;
    const int c0  = blockIdx.y * 32;
    const int n   = blockIdx.z;
    const int tx = threadIdx.x, ty = threadIdx.y;
    const float* xp = x + ((size_t)n*CIN + c0)*HW + hw0;
    #pragma unroll
    for (int i = ty; i < 32; i += 8)
        tile[i][tx] = xp[(size_t)i*HW + tx];
    __syncthreads();
    const int t = ty*32 + tx;
    const int hwl = t >> 3, q = t & 7;
    ushort4 v;
    v.x = __bfloat16_as_ushort(__float2bfloat16(tile[q*4+0][hwl]));
    v.y = __bfloat16_as_ushort(__float2bfloat16(tile[q*4+1][hwl]));
    v.z = __bfloat16_as_ushort(__float2bfloat16(tile[q*4+2][hwl]));
    v.w = __bfloat16_as_ushort(__float2bfloat16(tile[q*4+3][hwl]));
    __hip_bfloat16* op = xt + ((size_t)n*HW + hw0 + hwl)*CIN + c0 + q*4;
    *(ushort4*)op = v;
}

// ---- pre-pass 2: weight OIHW f32 -> [oc][(kh*3+kw)*128+ic] bf16 ----
__global__ void wcast(const float* __restrict__ w, __hip_bfloat16* __restrict__ wt) {
    int tid = blockIdx.x*256 + threadIdx.x;
    if (tid >= OCH*KSZ) return;
    int oc = tid / KSZ, r = tid % KSZ;
    int pos = r >> 7, ic = r & 127;
    wt[tid] = __float2bfloat16(w[((size_t)(oc*CIN + ic))*9 + pos]);
}

// ---- main: implicit-GEMM bf16 MFMA conv ----
// grid (365), block 512 = 8 waves (2M x 4N), per-wave 128x64.
// BK=32, triple buffer (3 x 32KB), ONE barrier + ONE counted vmcnt per K-tile;
// waves free-run within a tile (double-buffer discipline makes intra-tile
// barriers unnecessary: stages only ever write buf[(ks+2)%3], reads only
// buf[ks%3]; boundary barrier + per-wave lgkmcnt(0)-before-MFMA publishes
// read-completion before any wave can issue the conflicting stage).
__global__ __launch_bounds__(512, 2)
void conv_mfma(const __hip_bfloat16* __restrict__ xt,
               const __hip_bfloat16* __restrict__ wt,
               const float* __restrict__ bias,
               float* __restrict__ out) {
    __shared__ uint4 smem[3*2048];   // 3 x (A 1024 + B 1024 granules) = 96KB

    const int t = threadIdx.x;
    // bijective XCD swizzle (m204): nwg=365, q=45, r=5
    {   }
    const int orig = blockIdx.x;
    const int xcd = orig & 7;
    const int tile = (xcd < 5 ? xcd*46 : 5*46 + (xcd-5)*45) + (orig >> 3);

    const int lane = t & 63, wid = t >> 6;
    const int wm = wid >> 2, wn = wid & 3;
    const int lr = lane & 15, lq = lane >> 4;

    // staging sources: unit = 1024 granules per matrix; thread t covers q=t, q=t+512
    // LDS layout per buffer: [A row 0..255 | B row 0..255] x 4 granules,
    // granule g holds logical k-quarter lq = g ^ ((row>>1)&3)  (2-way banks, free)
    const __hip_bfloat16* aptr[2];
    const __hip_bfloat16* bptr[2];
    #pragma unroll
    for (int i = 0; i < 2; ++i) {
        int q = i*512 + t;
        int row = q >> 2, j = q & 3;
        int ls = j ^ ((row >> 1) & 3);
        aptr[i] = wt + (size_t)row*KSZ + ls*8;
        int colg = tile*BN + row; if (colg >= TOTC) colg = TOTC - 1;
        int n = colg / SPB, rem = colg - n*SPB;
        int oh = rem / OHW, ow = rem - oh*OHW;
        bptr[i] = xt + ((size_t)(n*HIN + oh)*HIN + ow)*CIN + ls*8;
    }

    auto issueT = [&](int ks) {      // 4 gl_lds: full tile ks -> buf[ks%3]
        uint4* dst = smem + (ks % 3)*2048;
        const int aoff = ks*BK;
        const int pos = ks >> 2;
        const int kh = pos / 3, kw = pos - kh*3;
        const int boff = (kh*HIN + kw)*CIN + (ks & 3)*32;
        gl_lds16(aptr[0] + aoff, dst + t);
        gl_lds16(aptr[1] + aoff, dst + 512 + t);
        gl_lds16(bptr[0] + boff, dst + 1024 + t);
        gl_lds16(bptr[1] + boff, dst + 1536 + t);
    };

    // per-lane read offsets (loop-invariant, granule units)
    int ao[8], bo[4];
    #pragma unroll
    for (int mi = 0; mi < 8; ++mi) {
        int ra = wm*128 + mi*16 + lr;
        ao[mi] = ra*4 + (lq ^ ((ra >> 1) & 3));
    }
    #pragma unroll
    for (int ni = 0; ni < 4; ++ni) {
        int rb = wn*64 + ni*16 + lr;
        bo[ni] = 1024 + rb*4 + (lq ^ ((rb >> 1) & 3));
    }

    f32x4 acc[8][4];
    #pragma unroll
    for (int i = 0; i < 8; ++i)
        #pragma unroll
        for (int j = 0; j < 4; ++j)
            acc[i][j] = (f32x4){0.f, 0.f, 0.f, 0.f};

    #define MFMA_BF16 __builtin_amdgcn_mfma_f32_16x16x32_bf16

    // prologue: tiles 0,1 in flight; certify 0, leave 1 flying
    issueT(0); issueT(1);
    asm volatile("s_waitcnt vmcnt(4)" ::: "memory");
    __builtin_amdgcn_s_barrier();
    __builtin_amdgcn_sched_barrier(0);

    for (int ks = 0; ks < NKS; ++ks) {
        const uint4* buf = smem + (ks % 3)*2048;
        bf16x8 a0[4], a1[4], b[4];
        #pragma unroll
        for (int mi = 0; mi < 4; ++mi) a0[mi] = *(bf16x8*)&buf[ao[mi]];
        #pragma unroll
        for (int ni = 0; ni < 4; ++ni) b[ni]  = *(bf16x8*)&buf[bo[ni]];
        if (ks + 2 < NKS) issueT(ks + 2);
        #pragma unroll
        for (int mi = 0; mi < 4; ++mi) a1[mi] = *(bf16x8*)&buf[ao[4 + mi]];

        asm volatile("s_waitcnt lgkmcnt(4)" ::: "memory");   // first 8 reads done
        __builtin_amdgcn_sched_barrier(0);
        __builtin_amdgcn_s_setprio(1);
        #pragma unroll
        for (int mi = 0; mi < 4; ++mi)
            #pragma unroll
            for (int ni = 0; ni < 4; ++ni)
                acc[mi][ni] = MFMA_BF16(a0[mi], b[ni], acc[mi][ni], 0, 0, 0);
        __builtin_amdgcn_s_setprio(0);

        asm volatile("s_waitcnt lgkmcnt(0)" ::: "memory");   // a1 reads done
        __builtin_amdgcn_sched_barrier(0);
        __builtin_amdgcn_s_setprio(1);
        #pragma unroll
        for (int mi = 0; mi < 4; ++mi)
            #pragma unroll
            for (int ni = 0; ni < 4; ++ni)
                acc[4+mi][ni] = MFMA_BF16(a1[mi], b[ni], acc[4+mi][ni], 0, 0, 0);
        __builtin_amdgcn_s_setprio(0);

        // tile boundary: certify buf[(ks+1)%3]; leave tile ks+2's 4 loads flying
        if (ks + 1 < NKS) {
            if (ks + 2 < NKS) asm volatile("s_waitcnt vmcnt(4)" ::: "memory");
            else              asm volatile("s_waitcnt vmcnt(0)" ::: "memory");
            __builtin_amdgcn_s_barrier();
            __builtin_amdgcn_sched_barrier(0);
        }
    }

    __syncthreads();

    // --- epilogue: LDS restage [64][260], coalesced float4 stores ---
    float (*eps)[260] = (float (*)[260])smem;
    const int cl4 = (t & 63) * 4;
    const int rsub = t >> 6;
    const int colg = tile*BN + cl4;
    int nn = 0, sp = 0;
    if (colg < TOTC) { nn = colg / SPB; sp = colg - nn*SPB; }
    #pragma unroll
    for (int h = 0; h < 4; ++h) {
        if (wm == (h >> 1)) {
            const int mib = (h & 1) * 4;
            #pragma unroll
            for (int ii = 0; ii < 4; ++ii) {
                int rl = ii*16 + lq*4;
                #pragma unroll
                for (int ni = 0; ni < 4; ++ni) {
                    int cl = wn*64 + ni*16 + lr;
                    #pragma unroll
                    for (int r = 0; r < 4; ++r)
                        eps[rl + r][cl] = acc[mib + ii][ni][r];
                }
            }
        }
        __syncthreads();
        if (colg < TOTC) {
            #pragma unroll
            for (int pass = 0; pass < 8; ++pass) {
                int rl = pass*8 + rsub;
                int rg = h*64 + rl;
                f32x4 v = *(f32x4*)&eps[rl][cl4];
                v = v + bias[rg];
                *(f32x4*)&out[((size_t)nn*OCH + rg)*SPB + sp] = v;
            }
        }
        __syncthreads();
    }
}

// ---- fallback: direct fp32 conv ----
__global__ void conv_naive(const float* __restrict__ x, const float* __restrict__ w,
                           const float* __restrict__ bias, float* __restrict__ out) {
    size_t tid = (size_t)blockIdx.x*256 + threadIdx.x;
    const size_t total = (size_t)NB*OCH*SPB;
    if (tid >= total) return;
    int col = (int)(tid % SPB);
    int oc  = (int)((tid / SPB) % OCH);
    int n   = (int)(tid / ((size_t)SPB*OCH));
    int oh = col / OHW, ow = col % OHW;
    float s = bias[oc];
    for (int ic = 0; ic < CIN; ++ic)
        #pragma unroll
        for (int kh = 0; kh < 3; ++kh)
            #pragma unroll
            for (int kw = 0; kw < 3; ++kw)
                s += x[((size_t)(n*CIN+ic)*HIN + oh+kh)*HIN + ow+kw]
                   * w[((size_t)(oc*CIN+ic)*3 + kh)*3 + kw];
    out[tid] = s;
}

extern "C" void kernel_launch(void* const* d_in, const int* in_sizes, int n_in,
                              void* d_out, int out_size, void* d_ws, size_t ws_size,
                              hipStream_t stream) {
    const float* x    = (const float*)d_in[0];
    const float* w    = (const float*)d_in[1];
    const float* bias = (const float*)d_in[2];
    float* out = (float*)d_out;

    const size_t xt_bytes = (size_t)NB*HW*CIN*sizeof(__hip_bfloat16);
    const size_t wt_bytes = (size_t)OCH*KSZ*sizeof(__hip_bfloat16);

    if (ws_size >= xt_bytes + wt_bytes) {
        __hip_bfloat16* xt  = (__hip_bfloat16*)d_ws;
        __hip_bfloat16* wtp = (__hip_bfloat16*)((char*)d_ws + xt_bytes);
        hipLaunchKernelGGL(xpose_cast, dim3(HW/32, CIN/32, NB), dim3(32, 8), 0, stream, x, xt);
        hipLaunchKernelGGL(wcast, dim3((OCH*KSZ + 255)/256), dim3(256), 0, stream, w, wtp);
        hipLaunchKernelGGL(conv_mfma, dim3(NT), dim3(512), 0, stream, xt, wtp, bias, out);
    } else {
        size_t total = (size_t)NB*OCH*SPB;
        hipLaunchKernelGGL(conv_naive, dim3((unsigned)((total + 255)/256)), dim3(256), 0, stream,
                           x, w, bias, out);
    }
}

// Round 8
// 85.824 us; speedup vs baseline: 1.1799x; 1.1027x over previous
//
#include <hip/hip_runtime.h>
#include <hip/hip_bf16.h>
#include <stdint.h>

#define NB    32
#define CIN   128
#define HIN   56
#define HW    (HIN*HIN)     // 3136
#define OCH   256
#define OHW   54
#define SPB   (OHW*OHW)     // 2916
#define KSZ   (CIN*9)       // 1152 = GEMM K
#define BM    256           // oc rows per block (= OCH)
#define BN    192           // flattened (n,sp) cols per block; 93312/192 = 486 exact
#define BK    32
#define NKS   (KSZ/BK)      // 36 K-tiles
#define TOTC  (NB*SPB)      // 93312
#define NT    486           // exact — no remainder tiles, no clamps
#define GRAN  ((BM+BN)*4)   // 1792 granules (16B) per buffer

typedef __attribute__((ext_vector_type(8))) short bf16x8;
typedef __attribute__((ext_vector_type(4))) float f32x4;

typedef __attribute__((address_space(1))) const uint32_t g_u32;
typedef __attribute__((address_space(3))) uint32_t l_u32;
static __device__ __forceinline__ void gl_lds16(const void* g, void* l) {
    __builtin_amdgcn_global_load_lds((g_u32*)g, (l_u32*)l, 16, 0, 0);
}

// ---- pre-pass 1: x NCHW f32 -> NHWC bf16 ----
__global__ void xpose_cast(const float* __restrict__ x, __hip_bfloat16* __restrict__ xt) {
    __shared__ float tile[32][33];
    const int hw0 = blockIdx.x * 32;
    const int c0  = blockIdx.y * 32;
    const int n   = blockIdx.z;
    const int tx = threadIdx.x, ty = threadIdx.y;
    const float* xp = x + ((size_t)n*CIN + c0)*HW + hw0;
    #pragma unroll
    for (int i = ty; i < 32; i += 8)
        tile[i][tx] = xp[(size_t)i*HW + tx];
    __syncthreads();
    const int t = ty*32 + tx;
    const int hwl = t >> 3, q = t & 7;
    ushort4 v;
    v.x = __bfloat16_as_ushort(__float2bfloat16(tile[q*4+0][hwl]));
    v.y = __bfloat16_as_ushort(__float2bfloat16(tile[q*4+1][hwl]));
    v.z = __bfloat16_as_ushort(__float2bfloat16(tile[q*4+2][hwl]));
    v.w = __bfloat16_as_ushort(__float2bfloat16(tile[q*4+3][hwl]));
    __hip_bfloat16* op = xt + ((size_t)n*HW + hw0 + hwl)*CIN + c0 + q*4;
    *(ushort4*)op = v;
}

// ---- pre-pass 2: weight OIHW f32 -> [oc][(kh*3+kw)*128+ic] bf16 ----
__global__ void wcast(const float* __restrict__ w, __hip_bfloat16* __restrict__ wt) {
    int tid = blockIdx.x*256 + threadIdx.x;
    if (tid >= OCH*KSZ) return;
    int oc = tid / KSZ, r = tid % KSZ;
    int pos = r >> 7, ic = r & 127;
    wt[tid] = __float2bfloat16(w[((size_t)(oc*CIN + ic))*9 + pos]);
}

// ---- main: implicit-GEMM bf16 MFMA conv ----
// grid (486), block 512 = 8 waves (2M x 4N), per-wave 128x48.
// BK=32, triple buffer (3 x 28KB = 84KB), ONE barrier + counted per-wave vmcnt
// per K-tile boundary; waves free-run within a tile.
__global__ __launch_bounds__(512, 2)
void conv_mfma(const __hip_bfloat16* __restrict__ xt,
               const __hip_bfloat16* __restrict__ wt,
               const float* __restrict__ bias,
               float* __restrict__ out) {
    __shared__ uint4 smem[3*GRAN];   // 86016 B

    const int t = threadIdx.x;
    // bijective XCD swizzle: nwg=486 = 8*60 + 6 -> q=60, r=6 (m204)
    const int orig = blockIdx.x;
    const int xcd = orig & 7;
    const int tile = (xcd < 6 ? xcd*61 : 6*61 + (xcd-6)*60) + (orig >> 3);

    const int lane = t & 63, wid = t >> 6;
    const int wm = wid >> 2, wn = wid & 3;     // per-wave 128 rows x 48 cols
    const int lr = lane & 15, lq = lane >> 4;

    // staging sources. LDS layout per buffer: [A rows 0..255 | B rows 0..191] x 4
    // granules; granule slot j holds logical k-quarter j ^ ((row>>1)&3)
    // (2-way bank aliasing = free; swizzle folded into per-lane SOURCE address)
    const __hip_bfloat16* aptr[2];   // A granules q = t, 512+t
    const __hip_bfloat16* bptr[2];   // B granules q = t, 512+t (latter only t<256)
    #pragma unroll
    for (int i = 0; i < 2; ++i) {
        int q = i*512 + t;
        int row = q >> 2, j = q & 3;
        int ls = j ^ ((row >> 1) & 3);
        aptr[i] = wt + (size_t)row*KSZ + ls*8;
        int br = q & 1023;                      // B rows: q=t (0..511 -> rows 0..127)
        // recompute for B domain: granule index within B region
        (void)br;
    }
    {
        // B sources computed separately (768 granules: i=0 all threads, i=1 t<256)
    }
    const __hip_bfloat16* bsrc0;
    const __hip_bfloat16* bsrc1;
    {
        int q0 = t;                  // granules 0..511   -> rows 0..127
        int r0 = q0 >> 2, j0 = q0 & 3, l0 = j0 ^ ((r0 >> 1) & 3);
        int c0 = tile*BN + r0;
        int n0 = c0 / SPB, rem0 = c0 - n0*SPB;
        bsrc0 = xt + ((size_t)(n0*HIN + rem0/OHW)*HIN + rem0%OHW)*CIN + l0*8;
        int q1 = 512 + (t & 255);    // granules 512..767 -> rows 128..191
        int r1 = q1 >> 2, j1 = q1 & 3, l1 = j1 ^ ((r1 >> 1) & 3);
        int c1 = tile*BN + r1;
        int n1 = c1 / SPB, rem1 = c1 - n1*SPB;
        bsrc1 = xt + ((size_t)(n1*HIN + rem1/OHW)*HIN + rem1%OHW)*CIN + l1*8;
    }

    auto issueT = [&](int ks) {      // tile ks -> buf[ks%3]; 4 loads (t<256) else 3
        uint4* dst = smem + (ks % 3)*GRAN;
        const int aoff = ks*BK;
        const int pos = ks >> 2;
        const int kh = pos / 3, kw = pos - kh*3;
        const int boff = (kh*HIN + kw)*CIN + (ks & 3)*32;
        gl_lds16(aptr[0] + aoff, dst + t);
        gl_lds16(aptr[1] + aoff, dst + 512 + t);
        gl_lds16(bsrc0 + boff, dst + 1024 + t);
        if (t < 256) gl_lds16(bsrc1 + boff, dst + 1536 + t);
    };

    // per-lane read offsets (granule units)
    int ao[8], bo[3];
    #pragma unroll
    for (int mi = 0; mi < 8; ++mi) {
        int ra = wm*128 + mi*16 + lr;
        ao[mi] = ra*4 + (lq ^ ((ra >> 1) & 3));
    }
    #pragma unroll
    for (int ni = 0; ni < 3; ++ni) {
        int rb = wn*48 + ni*16 + lr;
        bo[ni] = 1024 + rb*4 + (lq ^ ((rb >> 1) & 3));
    }

    f32x4 acc[8][3];
    #pragma unroll
    for (int i = 0; i < 8; ++i)
        #pragma unroll
        for (int j = 0; j < 3; ++j)
            acc[i][j] = (f32x4){0.f, 0.f, 0.f, 0.f};

    #define MFMA_BF16 __builtin_amdgcn_mfma_f32_16x16x32_bf16
    #define VM_OWN() do { \
        if (wid < 4) asm volatile("s_waitcnt vmcnt(4)" ::: "memory"); \
        else         asm volatile("s_waitcnt vmcnt(3)" ::: "memory"); } while (0)

    // prologue: tiles 0,1 in flight; certify 0, leave 1 flying
    issueT(0); issueT(1);
    VM_OWN();
    __builtin_amdgcn_s_barrier();
    __builtin_amdgcn_sched_barrier(0);

    for (int ks = 0; ks < NKS; ++ks) {
        const uint4* buf = smem + (ks % 3)*GRAN;
        bf16x8 a0[4], a1[4], b[3];
        #pragma unroll
        for (int mi = 0; mi < 4; ++mi) a0[mi] = *(bf16x8*)&buf[ao[mi]];
        #pragma unroll
        for (int ni = 0; ni < 3; ++ni) b[ni]  = *(bf16x8*)&buf[bo[ni]];
        if (ks + 2 < NKS) issueT(ks + 2);
        #pragma unroll
        for (int mi = 0; mi < 4; ++mi) a1[mi] = *(bf16x8*)&buf[ao[4 + mi]];

        asm volatile("s_waitcnt lgkmcnt(4)" ::: "memory");   // first 7 reads done
        __builtin_amdgcn_sched_barrier(0);
        __builtin_amdgcn_s_setprio(1);
        #pragma unroll
        for (int mi = 0; mi < 4; ++mi)
            #pragma unroll
            for (int ni = 0; ni < 3; ++ni)
                acc[mi][ni] = MFMA_BF16(a0[mi], b[ni], acc[mi][ni], 0, 0, 0);
        __builtin_amdgcn_s_setprio(0);

        asm volatile("s_waitcnt lgkmcnt(0)" ::: "memory");   // a1 reads done
        __builtin_amdgcn_sched_barrier(0);
        __builtin_amdgcn_s_setprio(1);
        #pragma unroll
        for (int mi = 0; mi < 4; ++mi)
            #pragma unroll
            for (int ni = 0; ni < 3; ++ni)
                acc[4+mi][ni] = MFMA_BF16(a1[mi], b[ni], acc[4+mi][ni], 0, 0, 0);
        __builtin_amdgcn_s_setprio(0);

        // boundary: certify buf[(ks+1)%3]; leave tile ks+2's loads flying
        if (ks + 1 < NKS) {
            if (ks + 2 < NKS) VM_OWN();
            else              asm volatile("s_waitcnt vmcnt(0)" ::: "memory");
            __builtin_amdgcn_s_barrier();
            __builtin_amdgcn_sched_barrier(0);
        }
    }

    __syncthreads();

    // --- epilogue: LDS restage [64][196] (2-way free), coalesced float4 stores ---
    float (*eps)[196] = (float (*)[196])smem;
    const int cl4 = (t % 48) * 4;                 // 0..188 (only t<384 store)
    const int rsub = t / 48;                      // 0..7 for t<384
    const int colg = tile*BN + cl4;               // always < TOTC (exact tiling)
    const int nn = colg / SPB;
    const int sp = colg - nn*SPB;                 // SPB%4==0 -> groups never straddle
    #pragma unroll
    for (int h = 0; h < 4; ++h) {
        if (wm == (h >> 1)) {
            const int mib = (h & 1) * 4;
            #pragma unroll
            for (int ii = 0; ii < 4; ++ii) {
                int rl = ii*16 + lq*4;
                #pragma unroll
                for (int ni = 0; ni < 3; ++ni) {
                    int cl = wn*48 + ni*16 + lr;
                    #pragma unroll
                    for (int r = 0; r < 4; ++r)
                        eps[rl + r][cl] = acc[mib + ii][ni][r];
                }
            }
        }
        __syncthreads();
        if (t < 384) {
            #pragma unroll
            for (int pass = 0; pass < 8; ++pass) {
                int rl = pass*8 + rsub;
                int rg = h*64 + rl;
                f32x4 v = *(f32x4*)&eps[rl][cl4];
                v = v + bias[rg];
                *(f32x4*)&out[((size_t)nn*OCH + rg)*SPB + sp] = v;
            }
        }
        __syncthreads();
    }
}

// ---- fallback: direct fp32 conv ----
__global__ void conv_naive(const float* __restrict__ x, const float* __restrict__ w,
                           const float* __restrict__ bias, float* __restrict__ out) {
    size_t tid = (size_t)blockIdx.x*256 + threadIdx.x;
    const size_t total = (size_t)NB*OCH*SPB;
    if (tid >= total) return;
    int col = (int)(tid % SPB);
    int oc  = (int)((tid / SPB) % OCH);
    int n   = (int)(tid / ((size_t)SPB*OCH));
    int oh = col / OHW, ow = col % OHW;
    float s = bias[oc];
    for (int ic = 0; ic < CIN; ++ic)
        #pragma unroll
        for (int kh = 0; kh < 3; ++kh)
            #pragma unroll
            for (int kw = 0; kw < 3; ++kw)
                s += x[((size_t)(n*CIN+ic)*HIN + oh+kh)*HIN + ow+kw]
                   * w[((size_t)(oc*CIN+ic)*3 + kh)*3 + kw];
    out[tid] = s;
}

extern "C" void kernel_launch(void* const* d_in, const int* in_sizes, int n_in,
                              void* d_out, int out_size, void* d_ws, size_t ws_size,
                              hipStream_t stream) {
    const float* x    = (const float*)d_in[0];
    const float* w    = (const float*)d_in[1];
    const float* bias = (const float*)d_in[2];
    float* out = (float*)d_out;

    const size_t xt_bytes = (size_t)NB*HW*CIN*sizeof(__hip_bfloat16);
    const size_t wt_bytes = (size_t)OCH*KSZ*sizeof(__hip_bfloat16);

    if (ws_size >= xt_bytes + wt_bytes) {
        __hip_bfloat16* xt  = (__hip_bfloat16*)d_ws;
        __hip_bfloat16* wtp = (__hip_bfloat16*)((char*)d_ws + xt_bytes);
        hipLaunchKernelGGL(xpose_cast, dim3(HW/32, CIN/32, NB), dim3(32, 8), 0, stream, x, xt);
        hipLaunchKernelGGL(wcast, dim3((OCH*KSZ + 255)/256), dim3(256), 0, stream, w, wtp);
        hipLaunchKernelGGL(conv_mfma, dim3(NT), dim3(512), 0, stream, xt, wtp, bias, out);
    } else {
        size_t total = (size_t)NB*OCH*SPB;
        hipLaunchKernelGGL(conv_naive, dim3((unsigned)((total + 255)/256)), dim3(256), 0, stream,
                           x, w, bias, out);
    }
}

// Round 9
// 82.731 us; speedup vs baseline: 1.2240x; 1.0374x over previous
//
#include <hip/hip_runtime.h>
#include <hip/hip_bf16.h>
#include <stdint.h>

#define NB    32
#define CIN   128
#define HIN   56
#define HW    (HIN*HIN)     // 3136
#define OCH   256
#define OHW   54
#define SPB   (OHW*OHW)     // 2916
#define KSZ   (CIN*9)       // 1152 = GEMM K
#define BM    256           // oc rows per block (= OCH)
#define BN    192           // flattened (n,sp) cols; 93312/192 = 486 exact
#define BK    64
#define NKS   (KSZ/BK)      // 18 K-tiles
#define TOTC  (NB*SPB)      // 93312
#define NT    486
#define GRAN  ((BM+BN)*8)   // 3584 granules (16B) per buffer = 56KB

typedef __attribute__((ext_vector_type(8))) short bf16x8;
typedef __attribute__((ext_vector_type(4))) float f32x4;

typedef __attribute__((address_space(1))) const uint32_t g_u32;
typedef __attribute__((address_space(3))) uint32_t l_u32;
static __device__ __forceinline__ void gl_lds16(const void* g, void* l) {
    __builtin_amdgcn_global_load_lds((g_u32*)g, (l_u32*)l, 16, 0, 0);
}

// ---- pre-pass 1: x NCHW f32 -> NHWC bf16 ----
__global__ void xpose_cast(const float* __restrict__ x, __hip_bfloat16* __restrict__ xt) {
    __shared__ float tile[32][33];
    const int hw0 = blockIdx.x * 32;
    const int c0  = blockIdx.y * 32;
    const int n   = blockIdx.z;
    const int tx = threadIdx.x, ty = threadIdx.y;
    const float* xp = x + ((size_t)n*CIN + c0)*HW + hw0;
    #pragma unroll
    for (int i = ty; i < 32; i += 8)
        tile[i][tx] = xp[(size_t)i*HW + tx];
    __syncthreads();
    const int t = ty*32 + tx;
    const int hwl = t >> 3, q = t & 7;
    ushort4 v;
    v.x = __bfloat16_as_ushort(__float2bfloat16(tile[q*4+0][hwl]));
    v.y = __bfloat16_as_ushort(__float2bfloat16(tile[q*4+1][hwl]));
    v.z = __bfloat16_as_ushort(__float2bfloat16(tile[q*4+2][hwl]));
    v.w = __bfloat16_as_ushort(__float2bfloat16(tile[q*4+3][hwl]));
    __hip_bfloat16* op = xt + ((size_t)n*HW + hw0 + hwl)*CIN + c0 + q*4;
    *(ushort4*)op = v;
}

// ---- pre-pass 2: weight OIHW f32 -> [oc][(kh*3+kw)*128+ic] bf16 ----
__global__ void wcast(const float* __restrict__ w, __hip_bfloat16* __restrict__ wt) {
    int tid = blockIdx.x*256 + threadIdx.x;
    if (tid >= OCH*KSZ) return;
    int oc = tid / KSZ, r = tid % KSZ;
    int pos = r >> 7, ic = r & 127;
    wt[tid] = __float2bfloat16(w[((size_t)(oc*CIN + ic))*9 + pos]);
}

// ---- main: implicit-GEMM bf16 MFMA conv ----
// grid (486), block 512 = 8 waves (2M x 4N), per-wave 128x48.
// BK=64, DOUBLE buffer (2 x 56KB), ONE barrier + vmcnt(0)-certify per K-tile
// (stages issued ~3/4 tile before the certify -> latency fully covered);
// free-running waves inside the tile with own-wave counted lgkm splits.
// LDS layout per buffer: [A rows 0..255 | B rows 0..191] x 8 granules/row,
// slot j of row holds logical k-chunk j ^ (row&7)  (bank-perfect: 8 words/bank).
__global__ __launch_bounds__(512, 2)
void conv_mfma(const __hip_bfloat16* __restrict__ xt,
               const __hip_bfloat16* __restrict__ wt,
               const float* __restrict__ bias,
               float* __restrict__ out) {
    __shared__ uint4 smem[2*GRAN];   // 114688 B

    const int t = threadIdx.x;
    // bijective XCD swizzle: nwg=486 = 8*60+6 -> q=60, r=6
    const int orig = blockIdx.x;
    const int xcd = orig & 7;
    const int tile = (xcd < 6 ? xcd*61 : 6*61 + (xcd-6)*60) + (orig >> 3);

    const int lane = t & 63, wid = t >> 6;
    const int wm = wid >> 2, wn = wid & 3;     // per-wave 128 rows x 48 cols
    const int lr = lane & 15, lq = lane >> 4;

    // staging sources: A granules q = i*512+t (i<4, 2048 total); B q = i*512+t (i<3, 1536)
    const __hip_bfloat16* aptr[4];
    #pragma unroll
    for (int i = 0; i < 4; ++i) {
        int q = i*512 + t;
        int row = q >> 3, j = q & 7;
        int ls = j ^ (row & 7);
        aptr[i] = wt + (size_t)row*KSZ + ls*8;
    }
    const __hip_bfloat16* bptr[3];
    #pragma unroll
    for (int i = 0; i < 3; ++i) {
        int q = i*512 + t;
        int row = q >> 3, j = q & 7;
        int ls = j ^ (row & 7);
        int colg = tile*BN + row;              // exact tiling: always < TOTC
        int n = colg / SPB, rem = colg - n*SPB;
        int oh = rem / OHW, ow = rem - oh*OHW;
        bptr[i] = xt + ((size_t)(n*HIN + oh)*HIN + ow)*CIN + ls*8;
    }

    auto issueT = [&](int ks) {      // 7 gl_lds: full tile ks -> buf[ks&1]
        uint4* dst = smem + (ks & 1)*GRAN;
        const int aoff = ks*BK;
        const int pos = ks >> 1;
        const int kh = pos / 3, kw = pos - kh*3;
        const int boff = (kh*HIN + kw)*CIN + (ks & 1)*64;
        #pragma unroll
        for (int i = 0; i < 4; ++i) gl_lds16(aptr[i] + aoff, dst + i*512 + t);
        #pragma unroll
        for (int i = 0; i < 3; ++i) gl_lds16(bptr[i] + boff, dst + 2048 + i*512 + t);
    };

    // per-lane read offsets (granule units), kk=0; kk=1 is ^4 (flips slot bit 2)
    int ao[8], bo[3];
    #pragma unroll
    for (int mi = 0; mi < 8; ++mi) {
        int ra = wm*128 + mi*16 + lr;
        ao[mi] = ra*8 + (lq ^ (ra & 7));
    }
    #pragma unroll
    for (int ni = 0; ni < 3; ++ni) {
        int rb = wn*48 + ni*16 + lr;
        bo[ni] = 2048 + rb*8 + (lq ^ (rb & 7));
    }

    f32x4 acc[8][3];
    #pragma unroll
    for (int i = 0; i < 8; ++i)
        #pragma unroll
        for (int j = 0; j < 3; ++j)
            acc[i][j] = (f32x4){0.f, 0.f, 0.f, 0.f};

    #define MFMA_BF16 __builtin_amdgcn_mfma_f32_16x16x32_bf16
    #define MFMA12(AARR, MIB, BARR) \
        __builtin_amdgcn_s_setprio(1); \
        _Pragma("unroll") \
        for (int ii = 0; ii < 4; ++ii) \
            _Pragma("unroll") \
            for (int ni = 0; ni < 3; ++ni) \
                acc[(MIB)+ii][ni] = MFMA_BF16(AARR[ii], BARR[ni], acc[(MIB)+ii][ni], 0, 0, 0); \
        __builtin_amdgcn_s_setprio(0);

    // prologue: tile 0 staged and certified
    issueT(0);
    asm volatile("s_waitcnt vmcnt(0)" ::: "memory");
    __builtin_amdgcn_s_barrier();
    __builtin_amdgcn_sched_barrier(0);

    for (int ks = 0; ks < NKS; ++ks) {
        const uint4* buf = smem + (ks & 1)*GRAN;
        bf16x8 a[4], a2[4], b[3];

        // ---- kk=0 ----
        #pragma unroll
        for (int mi = 0; mi < 4; ++mi) a[mi] = *(bf16x8*)&buf[ao[mi]];
        #pragma unroll
        for (int ni = 0; ni < 3; ++ni) b[ni] = *(bf16x8*)&buf[bo[ni]];
        if (ks + 1 < NKS) issueT(ks + 1);          // ~3/4-tile flight before certify
        #pragma unroll
        for (int mi = 0; mi < 4; ++mi) a2[mi] = *(bf16x8*)&buf[ao[4 + mi]];

        asm volatile("s_waitcnt lgkmcnt(4)" ::: "memory");   // a,b done
        __builtin_amdgcn_sched_barrier(0);
        MFMA12(a, 0, b)
        asm volatile("s_waitcnt lgkmcnt(0)" ::: "memory");   // a2 done
        __builtin_amdgcn_sched_barrier(0);
        MFMA12(a2, 4, b)

        // ---- kk=1 ----
        #pragma unroll
        for (int mi = 0; mi < 4; ++mi) a[mi] = *(bf16x8*)&buf[ao[mi] ^ 4];
        #pragma unroll
        for (int ni = 0; ni < 3; ++ni) b[ni] = *(bf16x8*)&buf[bo[ni] ^ 4];
        #pragma unroll
        for (int mi = 0; mi < 4; ++mi) a2[mi] = *(bf16x8*)&buf[ao[4 + mi] ^ 4];

        asm volatile("s_waitcnt lgkmcnt(4)" ::: "memory");
        __builtin_amdgcn_sched_barrier(0);
        MFMA12(a, 0, b)
        asm volatile("s_waitcnt lgkmcnt(0)" ::: "memory");
        __builtin_amdgcn_sched_barrier(0);
        MFMA12(a2, 4, b)

        // boundary: certify buf[(ks+1)&1] (stages landed long ago), one barrier
        if (ks + 1 < NKS) {
            asm volatile("s_waitcnt vmcnt(0)" ::: "memory");
            __builtin_amdgcn_s_barrier();
            __builtin_amdgcn_sched_barrier(0);
        }
    }

    __syncthreads();

    // --- epilogue: LDS restage [64][196] (2-way free), coalesced float4 stores ---
    float (*eps)[196] = (float (*)[196])smem;
    const int cl4 = (t % 48) * 4;                 // 0..188
    const int rsub = t / 48;                      // 0..7 for t<384
    const int colg = tile*BN + cl4;
    const int nn = colg / SPB;
    const int sp = colg - nn*SPB;                 // SPB%4==0 -> no straddle
    #pragma unroll
    for (int h = 0; h < 4; ++h) {
        if (wm == (h >> 1)) {
            const int mib = (h & 1) * 4;
            #pragma unroll
            for (int ii = 0; ii < 4; ++ii) {
                int rl = ii*16 + lq*4;
                #pragma unroll
                for (int ni = 0; ni < 3; ++ni) {
                    int cl = wn*48 + ni*16 + lr;
                    #pragma unroll
                    for (int r = 0; r < 4; ++r)
                        eps[rl + r][cl] = acc[mib + ii][ni][r];
                }
            }
        }
        __syncthreads();
        if (t < 384) {
            #pragma unroll
            for (int pass = 0; pass < 8; ++pass) {
                int rl = pass*8 + rsub;
                int rg = h*64 + rl;
                f32x4 v = *(f32x4*)&eps[rl][cl4];
                v = v + bias[rg];
                *(f32x4*)&out[((size_t)nn*OCH + rg)*SPB + sp] = v;
            }
        }
        __syncthreads();
    }
}

// ---- fallback: direct fp32 conv ----
__global__ void conv_naive(const float* __restrict__ x, const float* __restrict__ w,
                           const float* __restrict__ bias, float* __restrict__ out) {
    size_t tid = (size_t)blockIdx.x*256 + threadIdx.x;
    const size_t total = (size_t)NB*OCH*SPB;
    if (tid >= total) return;
    int col = (int)(tid % SPB);
    int oc  = (int)((tid / SPB) % OCH);
    int n   = (int)(tid / ((size_t)SPB*OCH));
    int oh = col / OHW, ow = col % OHW;
    float s = bias[oc];
    for (int ic = 0; ic < CIN; ++ic)
        #pragma unroll
        for (int kh = 0; kh < 3; ++kh)
            #pragma unroll
            for (int kw = 0; kw < 3; ++kw)
                s += x[((size_t)(n*CIN+ic)*HIN + oh+kh)*HIN + ow+kw]
                   * w[((size_t)(oc*CIN+ic)*3 + kh)*3 + kw];
    out[tid] = s;
}

extern "C" void kernel_launch(void* const* d_in, const int* in_sizes, int n_in,
                              void* d_out, int out_size, void* d_ws, size_t ws_size,
                              hipStream_t stream) {
    const float* x    = (const float*)d_in[0];
    const float* w    = (const float*)d_in[1];
    const float* bias = (const float*)d_in[2];
    float* out = (float*)d_out;

    const size_t xt_bytes = (size_t)NB*HW*CIN*sizeof(__hip_bfloat16);
    const size_t wt_bytes = (size_t)OCH*KSZ*sizeof(__hip_bfloat16);

    if (ws_size >= xt_bytes + wt_bytes) {
        __hip_bfloat16* xt  = (__hip_bfloat16*)d_ws;
        __hip_bfloat16* wtp = (__hip_bfloat16*)((char*)d_ws + xt_bytes);
        hipLaunchKernelGGL(xpose_cast, dim3(HW/32, CIN/32, NB), dim3(32, 8), 0, stream, x, xt);
        hipLaunchKernelGGL(wcast, dim3((OCH*KSZ + 255)/256), dim3(256), 0, stream, w, wtp);
        hipLaunchKernelGGL(conv_mfma, dim3(NT), dim3(512), 0, stream, xt, wtp, bias, out);
    } else {
        size_t total = (size_t)NB*OCH*SPB;
        hipLaunchKernelGGL(conv_naive, dim3((unsigned)((total + 255)/256)), dim3(256), 0, stream,
                           x, w, bias, out);
    }
}